// Round 1
// baseline (19848.296 us; speedup 1.0000x reference)
//
#include <hip/hip_runtime.h>

#define LSEQ 512
#define NIN 1024
#define NH 2048
#define NV 50257
#define NG 8192  /* 4*NH */

// ---------------------------------------------------------------------------
// GEMM: C[M,N] = A[M,K] @ B[N,K]^T + bias1[n] (+ bias2[n] if non-null)
// BM=BN=128, BK=32, 256 threads, 8x8 microtile per thread. fp32.
// M must be a multiple of 128 (true here: M=512); N,K arbitrary with N-edge
// masking (K always a multiple of 32 here: 1024/2048).
// ---------------------------------------------------------------------------
__global__ __launch_bounds__(256, 2)
void gemm_abT(const float* __restrict__ A, const float* __restrict__ B,
              const float* __restrict__ bias1, const float* __restrict__ bias2,
              float* __restrict__ C, int M, int N, int K)
{
    __shared__ float As[32][128];   // [k][m]
    __shared__ float Bs[32][128];   // [k][n]
    const int tid = threadIdx.x;
    const int m0 = blockIdx.y * 128;
    const int n0 = blockIdx.x * 128;
    const int tx = tid & 15;        // n-dir
    const int ty = tid >> 4;        // m-dir
    const int lrow = tid >> 1;      // 0..127 row to load
    const int lk0  = (tid & 1) << 4; // 0 or 16

    float acc[8][8];
#pragma unroll
    for (int i = 0; i < 8; ++i)
#pragma unroll
        for (int j = 0; j < 8; ++j) acc[i][j] = 0.f;

    const bool bvalid = (n0 + lrow) < N;

    for (int k0 = 0; k0 < K; k0 += 32) {
        // load A tile (rows always valid: M multiple of 128)
        float4 va[4], vb[4];
        {
            const float* pa = A + (size_t)(m0 + lrow) * K + k0 + lk0;
#pragma unroll
            for (int q = 0; q < 4; ++q) va[q] = *(const float4*)(pa + 4 * q);
        }
#pragma unroll
        for (int q = 0; q < 4; ++q) vb[q] = make_float4(0.f, 0.f, 0.f, 0.f);
        if (bvalid) {
            const float* pb = B + (size_t)(n0 + lrow) * K + k0 + lk0;
#pragma unroll
            for (int q = 0; q < 4; ++q) vb[q] = *(const float4*)(pb + 4 * q);
        }
#pragma unroll
        for (int q = 0; q < 4; ++q) {
            As[lk0 + 4 * q + 0][lrow] = va[q].x;
            As[lk0 + 4 * q + 1][lrow] = va[q].y;
            As[lk0 + 4 * q + 2][lrow] = va[q].z;
            As[lk0 + 4 * q + 3][lrow] = va[q].w;
            Bs[lk0 + 4 * q + 0][lrow] = vb[q].x;
            Bs[lk0 + 4 * q + 1][lrow] = vb[q].y;
            Bs[lk0 + 4 * q + 2][lrow] = vb[q].z;
            Bs[lk0 + 4 * q + 3][lrow] = vb[q].w;
        }
        __syncthreads();

#pragma unroll 4
        for (int kk = 0; kk < 32; ++kk) {
            const float4 a0 = *(const float4*)&As[kk][ty * 8];
            const float4 a1 = *(const float4*)&As[kk][ty * 8 + 4];
            const float4 b0 = *(const float4*)&Bs[kk][tx * 8];
            const float4 b1 = *(const float4*)&Bs[kk][tx * 8 + 4];
            const float av[8] = {a0.x, a0.y, a0.z, a0.w, a1.x, a1.y, a1.z, a1.w};
            const float bv[8] = {b0.x, b0.y, b0.z, b0.w, b1.x, b1.y, b1.z, b1.w};
#pragma unroll
            for (int i = 0; i < 8; ++i)
#pragma unroll
                for (int j = 0; j < 8; ++j)
                    acc[i][j] = fmaf(av[i], bv[j], acc[i][j]);
        }
        __syncthreads();
    }

#pragma unroll
    for (int j = 0; j < 8; ++j) {
        const int n = n0 + tx * 8 + j;
        if (n >= N) continue;
        const float bb = bias1[n] + (bias2 ? bias2[n] : 0.f);
#pragma unroll
        for (int i = 0; i < 8; ++i) {
            const int m = m0 + ty * 8 + i;
            C[(size_t)m * N + n] = acc[i][j] + bb;
        }
    }
}

// ---------------------------------------------------------------------------
// Persistent sequential LSTM kernel.
// 256 WGs (one per CU), 512 threads each. WG k owns hidden units [8k, 8k+8)
// i.e. gate rows {g*2048 + 8k + u : g in 0..3, u in 0..7} = 32 rows.
// Each thread holds 128 fp32 W_hh weights in REGISTERS (32 rows x 2048 cols
// / 512 threads); weights are loaded once per phase (encoder/decoder).
// Per step: stage h (8KB) to LDS, 128 FMA/thread, 16-lane shuffle reduce,
// gate nonlinearity on 8 threads, grid barrier (atomic counter).
// ---------------------------------------------------------------------------
__device__ __forceinline__ float sigmoidf_(float x)
{
    return 1.f / (1.f + __expf(-x));
}

__device__ __forceinline__ void grid_barrier(unsigned int* counter, unsigned int target)
{
    __syncthreads();
    if (threadIdx.x == 0) {
        __threadfence();  // release: flush L1 + write back L2 (agent scope)
        __hip_atomic_fetch_add(counter, 1u, __ATOMIC_RELAXED, __HIP_MEMORY_SCOPE_AGENT);
        while (__hip_atomic_load(counter, __ATOMIC_RELAXED, __HIP_MEMORY_SCOPE_AGENT) < target) {
            __builtin_amdgcn_s_sleep(2);
        }
        __threadfence();  // acquire: invalidate L1/L2 so fresh h is visible
    }
    __syncthreads();
}

__global__ __launch_bounds__(512, 2)
void seq_lstm(const float* __restrict__ Whh_e,
              const float* __restrict__ Whh_d,
              const float* __restrict__ Xe,   // [LSEQ][NG] = Wih_e@src + biases
              const float* __restrict__ Xd,   // [LSEQ][NG]
              float* __restrict__ hbuf,       // [2][NH] double-buffered h
              float* __restrict__ Hd,         // [LSEQ][NH] decoder h history
              unsigned int* __restrict__ counter)
{
    const int wg   = blockIdx.x;        // 0..255
    const int tid  = threadIdx.x;       // 0..511
    const int lane = tid & 63;
    const int wv   = tid >> 6;          // 0..7
    const int row  = (wv << 2) + (lane >> 4);  // local gate-row 0..31
    const int sub  = lane & 15;                // 16 threads per row
    const int gate = row >> 3;
    const int u    = row & 7;
    const int grow = gate * NH + wg * 8 + u;   // global gate row in [0,8192)
    const int hbase = sub * 132;               // swizzled LDS base (pad 4/seg)

    __shared__ float h_s[2112];   // 2048 + 16*4 pad (kills 128-stride conflicts)
    __shared__ float gates_s[32];
    __shared__ float c_s[8];

    // --- load encoder recurrent weights into registers ---
    float w[128];
    {
        const float* wp = Whh_e + (size_t)grow * NH + sub * 128;
#pragma unroll
        for (int q = 0; q < 32; ++q) {
            const float4 v = *(const float4*)(wp + 4 * q);
            w[4 * q + 0] = v.x; w[4 * q + 1] = v.y;
            w[4 * q + 2] = v.z; w[4 * q + 3] = v.w;
        }
    }

    if (tid < 8) {
        c_s[tid] = 0.f;
        hbuf[wg * 8 + tid] = 0.f;   // h0 = 0 in buffer 0
    }

    unsigned int bidx = 1;
    grid_barrier(counter, 256u * bidx); ++bidx;

#pragma unroll 1
    for (int gs = 0; gs < 2 * LSEQ; ++gs) {
        if (gs == LSEQ) {
            // switch to decoder weights (h,c carry over = "memory")
            const float* wp = Whh_d + (size_t)grow * NH + sub * 128;
#pragma unroll
            for (int q = 0; q < 32; ++q) {
                const float4 v = *(const float4*)(wp + 4 * q);
                w[4 * q + 0] = v.x; w[4 * q + 1] = v.y;
                w[4 * q + 2] = v.z; w[4 * q + 3] = v.w;
            }
        }

        // stage h (2048 f32) into LDS, swizzled: phys = idx + (idx>>7)*4
        {
            const float4 hv = *(const float4*)(hbuf + (gs & 1) * NH + tid * 4);
            *(float4*)&h_s[tid * 4 + ((tid >> 5) << 2)] = hv;
        }
        __syncthreads();

        // matvec partial: this thread's 128 columns of its gate row
        float partial = 0.f;
#pragma unroll
        for (int ch = 0; ch < 8; ++ch) {
            const float4 h0 = *(const float4*)&h_s[hbase + ch * 16 + 0];
            const float4 h1 = *(const float4*)&h_s[hbase + ch * 16 + 4];
            const float4 h2 = *(const float4*)&h_s[hbase + ch * 16 + 8];
            const float4 h3 = *(const float4*)&h_s[hbase + ch * 16 + 12];
            const int b = ch * 16;
            partial += w[b + 0] * h0.x + w[b + 1] * h0.y + w[b + 2] * h0.z + w[b + 3] * h0.w
                     + w[b + 4] * h1.x + w[b + 5] * h1.y + w[b + 6] * h1.z + w[b + 7] * h1.w
                     + w[b + 8] * h2.x + w[b + 9] * h2.y + w[b +10] * h2.z + w[b +11] * h2.w
                     + w[b +12] * h3.x + w[b +13] * h3.y + w[b +14] * h3.z + w[b +15] * h3.w;
        }
        // reduce across the 16 lanes of this row
        partial += __shfl_xor(partial, 1);
        partial += __shfl_xor(partial, 2);
        partial += __shfl_xor(partial, 4);
        partial += __shfl_xor(partial, 8);
        if (sub == 0) {
            const float xc = (gs < LSEQ)
                ? Xe[(size_t)gs * NG + grow]
                : Xd[(size_t)(gs - LSEQ) * NG + grow];
            gates_s[row] = partial + xc;
        }
        __syncthreads();

        if (tid < 8) {
            const float ig = sigmoidf_(gates_s[tid]);
            const float fg = sigmoidf_(gates_s[8 + tid]);
            const float gg = tanhf(gates_s[16 + tid]);
            const float og = sigmoidf_(gates_s[24 + tid]);
            const float cn = fg * c_s[tid] + ig * gg;
            c_s[tid] = cn;
            const float hn = og * tanhf(cn);
            if (gs >= LSEQ)
                Hd[(size_t)(gs - LSEQ) * NH + wg * 8 + tid] = hn;
            if (gs < 2 * LSEQ - 1)
                hbuf[((gs + 1) & 1) * NH + wg * 8 + tid] = hn;
        }

        if (gs < 2 * LSEQ - 1) {
            grid_barrier(counter, 256u * bidx); ++bidx;
        }
    }
}

// ---------------------------------------------------------------------------
extern "C" void kernel_launch(void* const* d_in, const int* in_sizes, int n_in,
                              void* d_out, int out_size, void* d_ws, size_t ws_size,
                              hipStream_t stream)
{
    const float* src   = (const float*)d_in[0];
    const float* tgt   = (const float*)d_in[1];
    const float* Wih_e = (const float*)d_in[2];
    const float* Whh_e = (const float*)d_in[3];
    const float* bih_e = (const float*)d_in[4];
    const float* bhh_e = (const float*)d_in[5];
    const float* Wih_d = (const float*)d_in[6];
    const float* Whh_d = (const float*)d_in[7];
    const float* bih_d = (const float*)d_in[8];
    const float* bhh_d = (const float*)d_in[9];
    const float* Wout  = (const float*)d_in[10];
    const float* bout  = (const float*)d_in[11];
    float* out = (float*)d_out;

    // workspace layout (bytes):
    //   [0, 4096)                        barrier counter (zeroed every call)
    //   [4096, 4096+16K)                 hbuf[2][2048]
    //   [+, +4MB)                        Hd[512][2048]
    //   [+, +16MB)                       Xe[512][8192]
    //   [+, +16MB)                       Xd[512][8192]
    char* ws = (char*)d_ws;
    unsigned int* counter = (unsigned int*)ws;
    float* hbuf = (float*)(ws + 4096);
    float* Hd   = (float*)(ws + 4096 + 16384);
    float* Xe   = (float*)(ws + 4096 + 16384 + (size_t)LSEQ * NH * 4);
    float* Xd   = Xe + (size_t)LSEQ * NG;

    hipMemsetAsync(ws, 0, 4096, stream);

    const dim3 blk(256);
    // input-side gate GEMMs (biases folded in)
    gemm_abT<<<dim3(NG / 128, LSEQ / 128), blk, 0, stream>>>(
        src, Wih_e, bih_e, bhh_e, Xe, LSEQ, NG, NIN);
    gemm_abT<<<dim3(NG / 128, LSEQ / 128), blk, 0, stream>>>(
        tgt, Wih_d, bih_d, bhh_d, Xd, LSEQ, NG, NIN);

    // sequential encoder+decoder (persistent, grid-resident)
    seq_lstm<<<dim3(256), dim3(512), 0, stream>>>(
        Whh_e, Whh_d, Xe, Xd, hbuf, Hd, counter);

    // output projection: Y = Hd @ Wout^T + bout
    gemm_abT<<<dim3((NV + 127) / 128, LSEQ / 128), blk, 0, stream>>>(
        Hd, Wout, bout, nullptr, out, LSEQ, NV, NH);
}